// Round 16
// baseline (176.068 us; speedup 1.0000x reference)
//
#include <hip/hip_runtime.h>
#include <math.h>

#define CAMS 6
#define CCH 256
#define HH 46
#define WW 80
#define NPIX (HH * WW)
#define HEADS 8
#define PIP 4
#define PP 4
#define KK 16
#define RADIUS_F 0.12f
#define NC 384        // combined qgemm output width: 256 offsets + 128 logits
#define FEATB (58 * 4 * CAMS)   // feat-transpose blocks in prep

__device__ __forceinline__ unsigned short f2bf(float f) {
    unsigned int x = __float_as_uint(f);
    unsigned int r = (x + 0x7FFFu + ((x >> 16) & 1u)) >> 16;  // RNE
    return (unsigned short)r;
}
__device__ __forceinline__ float bf2f(unsigned short u) {
    return __uint_as_float(((unsigned int)u) << 16);
}

// prep4_k:
//  [0, FEATB)        : LDS-tiled feat transpose + bf16 convert
//  [FEATB, FEATB+40) : weight transposes -> f4[kg][col] = W[col][4kg..4kg+3]
__global__ void __launch_bounds__(256) prep4_k(const float* __restrict__ imfeat,
                                               unsigned short* __restrict__ feat_t,
                                               const float* __restrict__ offw,
                                               const float* __restrict__ ww,
                                               const float* __restrict__ outw,
                                               float* __restrict__ WCi,
                                               float* __restrict__ outTi) {
    __shared__ float tile[64][65];
    int b = blockIdx.x;
    int tj = threadIdx.x & 63;
    int ti = threadIdx.x >> 6;
    if (b < FEATB) {
        int px = b % 58, rest = b / 58;
        int r0 = (rest % 4) * 64;
        int cam = rest / 4;
        int p0 = px * 64;
        const float* src = imfeat + ((long)cam * CCH + r0) * NPIX + p0;
#pragma unroll
        for (int k = 0; k < 64; k += 4) {
            if (p0 + tj < NPIX) tile[ti + k][tj] = src[(long)(ti + k) * NPIX + tj];
        }
        __syncthreads();
        unsigned short* dst = feat_t + ((long)cam * NPIX + p0) * CCH + r0;
#pragma unroll
        for (int k = 0; k < 64; k += 4) {
            if (p0 + ti + k < NPIX) dst[(long)(ti + k) * CCH + tj] = f2bf(tile[tj][ti + k]);
        }
    } else {
        int c = b - FEATB;
        const float* src;
        float* dst;
        int tr, tc, dcols, dcol0;
        if (c < 16)      { src = offw; dst = WCi;   tr = c >> 2;        tc = c & 3;         dcols = NC;  dcol0 = 0; }
        else if (c < 24) { src = ww;   dst = WCi;   tr = (c - 16) & 1;  tc = (c - 16) >> 1; dcols = NC;  dcol0 = 256; }
        else             { src = outw; dst = outTi; tr = (c - 24) >> 2; tc = (c - 24) & 3;  dcols = 256; dcol0 = 0; }
#pragma unroll
        for (int k = 0; k < 64; k += 4)
            tile[ti + k][tj] = src[(long)(tr * 64 + ti + k) * CCH + tc * 64 + tj];
        __syncthreads();
        int col = dcol0 + tr * 64 + tj;
#pragma unroll
        for (int q = ti; q < 16; q += 4) {
            float4 v = make_float4(tile[tj][4 * q + 0], tile[tj][4 * q + 1],
                                   tile[tj][4 * q + 2], tile[tj][4 * q + 3]);
            ((float4*)dst)[(long)(tc * 16 + q) * dcols + col] = v;
        }
    }
}

// Dense layer 1: grid (313, 3); block = 8n x 128c; thread = 1n x 4c.
// min 8 waves/EU -> 32 waves/CU for latency hiding.
__global__ void __launch_bounds__(256, 8) qgemm14_k(const float* __restrict__ query,
                                                    const float* __restrict__ WCi,  // f4[64][384]
                                                    const float* __restrict__ offB,
                                                    const float* __restrict__ wB,
                                                    float* __restrict__ offsets,    // [N][256]
                                                    float* __restrict__ wl,         // [N][128]
                                                    int N) {
    __shared__ float4 a_lds[64][9];   // [kg][n_local], pad 9
    int t = threadIdx.x;
    int n0 = blockIdx.x * 8;
    int colg = blockIdx.y;            // 0..2
    int nn = t >> 5;                  // n_local 0..7
    int k4 = t & 31;
    {
        int n = n0 + nn;
        const float4* qr = (const float4*)(query + (long)min(n, N - 1) * CCH);
        float4 v0 = qr[k4];
        float4 v1 = qr[k4 + 32];
        bool ok = n < N;
        a_lds[k4][nn] = ok ? v0 : make_float4(0.f, 0.f, 0.f, 0.f);
        a_lds[k4 + 32][nn] = ok ? v1 : make_float4(0.f, 0.f, 0.f, 0.f);
    }
    __syncthreads();

    int cl = k4;
    const float4* wp = (const float4*)WCi + colg * 128 + cl;
    float acc[4] = {0.f, 0.f, 0.f, 0.f};

#pragma unroll 2
    for (int kg = 0; kg < 64; kg++) {
        float4 a = a_lds[kg][nn];
        const float4* wk = wp + (long)kg * NC;
#pragma unroll
        for (int j = 0; j < 4; j++) {
            float4 wv = wk[32 * j];
            acc[j] = fmaf(a.w, wv.w, fmaf(a.z, wv.z, fmaf(a.y, wv.y, fmaf(a.x, wv.x, acc[j]))));
        }
    }

    int n = n0 + nn;
    if (n < N) {
        if (colg < 2) {
#pragma unroll
            for (int j = 0; j < 4; j++) {
                int col = colg * 128 + cl + 32 * j;
                offsets[(long)n * CCH + col] = tanhf(acc[j] + offB[col]) * RADIUS_F;
            }
        } else {
#pragma unroll
            for (int j = 0; j < 4; j++) {
                int c2 = cl + 32 * j;
                wl[(long)n * 128 + c2] = acc[j] + wB[c2];
            }
        }
    }
}

// Per-(cam,query) sampling. One wave per task; XCD-pinned task ranges.
// min 8 waves/EU -> 32 waves/CU: double the outstanding scattered loads
// (kernel is latency-bound: VALU floor ~10us, was running ~50us at 16 w/CU).
__global__ void __launch_bounds__(256, 8) sample_cam_k(
        const unsigned short* __restrict__ feat_t,  // [CAMS][NPIX][CCH] bf16
        const float* __restrict__ refp,             // [CAMS][N][PIP][2]
        const int* __restrict__ bev,                // [CAMS][N][PIP]
        const float* __restrict__ offsets,          // [N][256]
        const float* __restrict__ wl,               // [N][128]
        float* __restrict__ cam_out,                // [CAMS][N][256]
        int N, int per_xcd) {
    int xcd = blockIdx.x & 7;
    int local = (blockIdx.x >> 3) * 4 + (threadIdx.x >> 6);
    if (local >= per_xcd) return;
    long task = (long)xcd * per_xcd + local;
    if (task >= (long)CAMS * N) return;
    int cam = (int)(task / N);
    int n = (int)(task - (long)cam * N);

    int l = threadIdx.x & 63;
    int h = l >> 3;

    const int* bv = bev + ((long)cam * N + n) * 4;
    int m0 = bv[0], m1 = bv[1], m2 = bv[2], m3 = bv[3];
    float* outp = cam_out + ((long)cam * N + n) * CCH + (l << 2);
    if (!(m0 | m1 | m2 | m3)) {
        *(float4*)outp = make_float4(0.f, 0.f, 0.f, 0.f);
        return;
    }

    const float* rp = refp + ((long)cam * N + n) * 8;
    const float4* offn = (const float4*)(offsets + (long)n * CCH + (h << 5));
    const float4* wln = (const float4*)(wl + (long)n * 128 + (h << 4));

    float4 wl0, wl1, wl2, wl3;
    float mmax = -1e30f;
    if (m0) { wl0 = wln[0]; mmax = fmaxf(mmax, fmaxf(fmaxf(wl0.x, wl0.y), fmaxf(wl0.z, wl0.w))); }
    if (m1) { wl1 = wln[1]; mmax = fmaxf(mmax, fmaxf(fmaxf(wl1.x, wl1.y), fmaxf(wl1.z, wl1.w))); }
    if (m2) { wl2 = wln[2]; mmax = fmaxf(mmax, fmaxf(fmaxf(wl2.x, wl2.y), fmaxf(wl2.z, wl2.w))); }
    if (m3) { wl3 = wln[3]; mmax = fmaxf(mmax, fmaxf(fmaxf(wl3.x, wl3.y), fmaxf(wl3.z, wl3.w))); }

    float w_[KK];
#pragma unroll
    for (int k = 0; k < KK; k++) w_[k] = 0.f;
    float ssum = 0.f;
    if (m0) {
        w_[0] = __expf(wl0.x - mmax); w_[1] = __expf(wl0.y - mmax);
        w_[2] = __expf(wl0.z - mmax); w_[3] = __expf(wl0.w - mmax);
        ssum += w_[0] + w_[1] + w_[2] + w_[3];
    }
    if (m1) {
        w_[4] = __expf(wl1.x - mmax); w_[5] = __expf(wl1.y - mmax);
        w_[6] = __expf(wl1.z - mmax); w_[7] = __expf(wl1.w - mmax);
        ssum += w_[4] + w_[5] + w_[6] + w_[7];
    }
    if (m2) {
        w_[8] = __expf(wl2.x - mmax); w_[9] = __expf(wl2.y - mmax);
        w_[10] = __expf(wl2.z - mmax); w_[11] = __expf(wl2.w - mmax);
        ssum += w_[8] + w_[9] + w_[10] + w_[11];
    }
    if (m3) {
        w_[12] = __expf(wl3.x - mmax); w_[13] = __expf(wl3.y - mmax);
        w_[14] = __expf(wl3.z - mmax); w_[15] = __expf(wl3.w - mmax);
        ssum += w_[12] + w_[13] + w_[14] + w_[15];
    }
    float inv = 1.f / ssum;

    const ushort4* fcam = (const ushort4*)(feat_t + (long)cam * NPIX * CCH) + l;
    float ax = 0.f, ay = 0.f, az = 0.f, aw = 0.f;

#pragma unroll
    for (int pip = 0; pip < PIP; pip++) {
        int vis = (pip == 0) ? m0 : (pip == 1) ? m1 : (pip == 2) ? m2 : m3;
        if (!vis) continue;
        float rx = rp[pip * 2 + 0];
        float ry = rp[pip * 2 + 1];
        float4 oa = offn[pip * 2];
        float4 ob = offn[pip * 2 + 1];
        float px[PP] = {oa.x, oa.z, ob.x, ob.z};
        float py[PP] = {oa.y, oa.w, ob.y, ob.w};
#pragma unroll
        for (int p = 0; p < PP; p++) {
            float wgt = w_[pip * PP + p];
            float x = fmaf(rx + px[p], (float)WW, -0.5f);
            float y = fmaf(ry + py[p], (float)HH, -0.5f);
            float x0f = floorf(x), y0f = floorf(y);
            float fx = x - x0f, fy = y - y0f;
            int ix = (int)x0f, iy = (int)y0f;
            int ix0 = min(max(ix, 0), WW - 1);
            int ix1 = min(max(ix + 1, 0), WW - 1);
            int iy0 = min(max(iy, 0), HH - 1);
            int iy1 = min(max(iy + 1, 0), HH - 1);
            float wx0 = (1.f - fx) * (((ix >= 0) & (ix < WW)) ? 1.f : 0.f);
            float wx1 = fx * (((ix + 1 >= 0) & (ix + 1 < WW)) ? 1.f : 0.f);
            float wy0 = (1.f - fy) * (((iy >= 0) & (iy < HH)) ? 1.f : 0.f);
            float wy1 = fy * (((iy + 1 >= 0) & (iy + 1 < HH)) ? 1.f : 0.f);
            const ushort4 u00 = fcam[(iy0 * WW + ix0) * (CCH / 4)];
            const ushort4 u01 = fcam[(iy0 * WW + ix1) * (CCH / 4)];
            const ushort4 u10 = fcam[(iy1 * WW + ix0) * (CCH / 4)];
            const ushort4 u11 = fcam[(iy1 * WW + ix1) * (CCH / 4)];
            float a00 = wgt * wy0 * wx0;
            float a01 = wgt * wy0 * wx1;
            float a10 = wgt * wy1 * wx0;
            float a11 = wgt * wy1 * wx1;
            ax = fmaf(a00, bf2f(u00.x), ax); ay = fmaf(a00, bf2f(u00.y), ay);
            az = fmaf(a00, bf2f(u00.z), az); aw = fmaf(a00, bf2f(u00.w), aw);
            ax = fmaf(a01, bf2f(u01.x), ax); ay = fmaf(a01, bf2f(u01.y), ay);
            az = fmaf(a01, bf2f(u01.z), az); aw = fmaf(a01, bf2f(u01.w), aw);
            ax = fmaf(a10, bf2f(u10.x), ax); ay = fmaf(a10, bf2f(u10.y), ay);
            az = fmaf(a10, bf2f(u10.z), az); aw = fmaf(a10, bf2f(u10.w), aw);
            ax = fmaf(a11, bf2f(u11.x), ax); ay = fmaf(a11, bf2f(u11.y), ay);
            az = fmaf(a11, bf2f(u11.z), az); aw = fmaf(a11, bf2f(u11.w), aw);
        }
    }
    *(float4*)outp = make_float4(ax * inv, ay * inv, az * inv, aw * inv);
}

// Dense layer 2 with fused 6-camera sum + count: grid (313, 2);
// block = 8n x 128c; thread = 1n x 4c. min 6 waves/EU (VGPR cap 85 keeps
// the 12-load staging burst unserialied).
__global__ void __launch_bounds__(256, 6) outfuse14_k(const float* __restrict__ camob,
                                                      const int* __restrict__ bev,
                                                      const float* __restrict__ outTi, // f4[64][256]
                                                      const float* __restrict__ outB,
                                                      float* __restrict__ out, int N) {
    __shared__ float4 a_lds[64][9];
    __shared__ float inv_s[8];
    int t = threadIdx.x;
    int n0 = blockIdx.x * 8;
    int colg = blockIdx.y;            // 0..1
    int nn = t >> 5;
    int k4 = t & 31;
    int n = n0 + nn;
    int ncl = min(n, N - 1);
    {
        float4 s0 = make_float4(0.f, 0.f, 0.f, 0.f);
        float4 s1 = make_float4(0.f, 0.f, 0.f, 0.f);
#pragma unroll
        for (int cam = 0; cam < CAMS; cam++) {
            const float4* cr = (const float4*)(camob + ((long)cam * N + ncl) * CCH);
            float4 v0 = cr[k4];
            float4 v1 = cr[k4 + 32];
            s0.x += v0.x; s0.y += v0.y; s0.z += v0.z; s0.w += v0.w;
            s1.x += v1.x; s1.y += v1.y; s1.z += v1.z; s1.w += v1.w;
        }
        bool ok = n < N;
        a_lds[k4][nn] = ok ? s0 : make_float4(0.f, 0.f, 0.f, 0.f);
        a_lds[k4 + 32][nn] = ok ? s1 : make_float4(0.f, 0.f, 0.f, 0.f);
    }
    if (k4 == 0) {
        int cnt = 0;
        const int4* bv4 = (const int4*)bev;
#pragma unroll
        for (int cam = 0; cam < CAMS; cam++) {
            int4 bv = bv4[(long)cam * N + ncl];
            cnt += (bv.x | bv.y | bv.z | bv.w) ? 1 : 0;
        }
        inv_s[nn] = 1.f / (float)max(cnt, 1);
    }
    __syncthreads();

    int cl = k4;
    const float4* wp = (const float4*)outTi + colg * 128 + cl;
    float acc[4] = {0.f, 0.f, 0.f, 0.f};

#pragma unroll 2
    for (int kg = 0; kg < 64; kg++) {
        float4 a = a_lds[kg][nn];
        const float4* wk = wp + (long)kg * 256;
#pragma unroll
        for (int j = 0; j < 4; j++) {
            float4 wv = wk[32 * j];
            acc[j] = fmaf(a.w, wv.w, fmaf(a.z, wv.z, fmaf(a.y, wv.y, fmaf(a.x, wv.x, acc[j]))));
        }
    }

    if (n < N) {
        float inv = inv_s[nn];
#pragma unroll
        for (int j = 0; j < 4; j++) {
            int col = colg * 128 + cl + 32 * j;
            out[(long)n * CCH + col] = fmaf(acc[j], inv, outB[col]);
        }
    }
}

extern "C" void kernel_launch(void* const* d_in, const int* in_sizes, int n_in,
                              void* d_out, int out_size, void* d_ws, size_t ws_size,
                              hipStream_t stream) {
    const float* query    = (const float*)d_in[0];
    const float* imfeat   = (const float*)d_in[1];
    const float* refp     = (const float*)d_in[2];
    const int*   bev      = (const int*)d_in[3];
    const float* offset_w = (const float*)d_in[4];
    const float* offset_b = (const float*)d_in[5];
    const float* weight_w = (const float*)d_in[6];
    const float* weight_b = (const float*)d_in[7];
    const float* out_w    = (const float*)d_in[8];
    const float* out_b    = (const float*)d_in[9];
    float* out = (float*)d_out;

    int N = in_sizes[0] / CCH;  // 2500

    float* ws = (float*)d_ws;
    unsigned short* feat_t = (unsigned short*)ws;              // 6*3680*256 bf16
    float* WCi    = ws + (size_t)CAMS * NPIX * CCH / 2;        // f4[64][384]
    float* outTi  = WCi + (size_t)CCH * NC;                    // f4[64][256]
    float* offs   = outTi + (size_t)CCH * CCH;                 // N*256
    float* wl     = offs + (size_t)N * CCH;                    // N*128
    float* camob  = wl + (size_t)N * 128;                      // CAMS*N*256

    prep4_k<<<FEATB + 40, 256, 0, stream>>>(imfeat, feat_t, offset_w, weight_w,
                                            out_w, WCi, outTi);

    int nb8 = (N + 7) / 8;   // 313
    qgemm14_k<<<dim3(nb8, 3), 256, 0, stream>>>(query, WCi, offset_b, weight_b,
                                                offs, wl, N);

    int T = CAMS * N;
    int per_xcd = (T + 7) / 8;
    int blocks = 8 * ((per_xcd + 3) / 4);
    sample_cam_k<<<blocks, 256, 0, stream>>>(feat_t, refp, bev, offs, wl, camob,
                                             N, per_xcd);

    outfuse14_k<<<dim3(nb8, 2), 256, 0, stream>>>(camob, bev, outTi, out_b, out, N);
}

// Round 17
// 105.472 us; speedup vs baseline: 1.6693x; 1.6693x over previous
//
#include <hip/hip_runtime.h>
#include <math.h>

#define CAMS 6
#define CCH 256
#define HH 46
#define WW 80
#define NPIX (HH * WW)
#define HEADS 8
#define PIP 4
#define PP 4
#define KK 16
#define RADIUS_F 0.12f
#define NC 384        // combined qgemm output width: 256 offsets + 128 logits
#define FEATB (58 * 4 * CAMS)   // feat-transpose blocks in prep

__device__ __forceinline__ unsigned short f2bf(float f) {
    unsigned int x = __float_as_uint(f);
    unsigned int r = (x + 0x7FFFu + ((x >> 16) & 1u)) >> 16;  // RNE
    return (unsigned short)r;
}
__device__ __forceinline__ float bf2f(unsigned short u) {
    return __uint_as_float(((unsigned int)u) << 16);
}

// prep4_k:
//  [0, FEATB)        : LDS-tiled feat transpose + bf16 convert
//  [FEATB, FEATB+40) : weight transposes -> f4[kg][col] = W[col][4kg..4kg+3]
__global__ void __launch_bounds__(256) prep4_k(const float* __restrict__ imfeat,
                                               unsigned short* __restrict__ feat_t,
                                               const float* __restrict__ offw,
                                               const float* __restrict__ ww,
                                               const float* __restrict__ outw,
                                               float* __restrict__ WCi,
                                               float* __restrict__ outTi) {
    __shared__ float tile[64][65];
    int b = blockIdx.x;
    int tj = threadIdx.x & 63;
    int ti = threadIdx.x >> 6;
    if (b < FEATB) {
        int px = b % 58, rest = b / 58;
        int r0 = (rest % 4) * 64;
        int cam = rest / 4;
        int p0 = px * 64;
        const float* src = imfeat + ((long)cam * CCH + r0) * NPIX + p0;
#pragma unroll
        for (int k = 0; k < 64; k += 4) {
            if (p0 + tj < NPIX) tile[ti + k][tj] = src[(long)(ti + k) * NPIX + tj];
        }
        __syncthreads();
        unsigned short* dst = feat_t + ((long)cam * NPIX + p0) * CCH + r0;
#pragma unroll
        for (int k = 0; k < 64; k += 4) {
            if (p0 + ti + k < NPIX) dst[(long)(ti + k) * CCH + tj] = f2bf(tile[tj][ti + k]);
        }
    } else {
        int c = b - FEATB;
        const float* src;
        float* dst;
        int tr, tc, dcols, dcol0;
        if (c < 16)      { src = offw; dst = WCi;   tr = c >> 2;        tc = c & 3;         dcols = NC;  dcol0 = 0; }
        else if (c < 24) { src = ww;   dst = WCi;   tr = (c - 16) & 1;  tc = (c - 16) >> 1; dcols = NC;  dcol0 = 256; }
        else             { src = outw; dst = outTi; tr = (c - 24) >> 2; tc = (c - 24) & 3;  dcols = 256; dcol0 = 0; }
#pragma unroll
        for (int k = 0; k < 64; k += 4)
            tile[ti + k][tj] = src[(long)(tr * 64 + ti + k) * CCH + tc * 64 + tj];
        __syncthreads();
        int col = dcol0 + tr * 64 + tj;
#pragma unroll
        for (int q = ti; q < 16; q += 4) {
            float4 v = make_float4(tile[tj][4 * q + 0], tile[tj][4 * q + 1],
                                   tile[tj][4 * q + 2], tile[tj][4 * q + 3]);
            ((float4*)dst)[(long)(tc * 16 + q) * dcols + col] = v;
        }
    }
}

// Dense layer 1: grid (313, 3); block = 8n x 128c; thread = 1n x 4c.
// No min-wave hint: compiler picks VGPR freely (no spills — round-16 lesson).
__global__ void __launch_bounds__(256) qgemm14_k(const float* __restrict__ query,
                                                 const float* __restrict__ WCi,  // f4[64][384]
                                                 const float* __restrict__ offB,
                                                 const float* __restrict__ wB,
                                                 float* __restrict__ offsets,    // [N][256]
                                                 float* __restrict__ wl,         // [N][128]
                                                 int N) {
    __shared__ float4 a_lds[64][9];   // [kg][n_local], pad 9
    int t = threadIdx.x;
    int n0 = blockIdx.x * 8;
    int colg = blockIdx.y;            // 0..2
    int nn = t >> 5;                  // n_local 0..7
    int k4 = t & 31;
    {
        int n = n0 + nn;
        const float4* qr = (const float4*)(query + (long)min(n, N - 1) * CCH);
        float4 v0 = qr[k4];
        float4 v1 = qr[k4 + 32];
        bool ok = n < N;
        a_lds[k4][nn] = ok ? v0 : make_float4(0.f, 0.f, 0.f, 0.f);
        a_lds[k4 + 32][nn] = ok ? v1 : make_float4(0.f, 0.f, 0.f, 0.f);
    }
    __syncthreads();

    int cl = k4;
    const float4* wp = (const float4*)WCi + colg * 128 + cl;
    float acc[4] = {0.f, 0.f, 0.f, 0.f};

#pragma unroll 2
    for (int kg = 0; kg < 64; kg++) {
        float4 a = a_lds[kg][nn];
        const float4* wk = wp + (long)kg * NC;
#pragma unroll
        for (int j = 0; j < 4; j++) {
            float4 wv = wk[32 * j];
            acc[j] = fmaf(a.w, wv.w, fmaf(a.z, wv.z, fmaf(a.y, wv.y, fmaf(a.x, wv.x, acc[j]))));
        }
    }

    int n = n0 + nn;
    if (n < N) {
        if (colg < 2) {
#pragma unroll
            for (int j = 0; j < 4; j++) {
                int col = colg * 128 + cl + 32 * j;
                offsets[(long)n * CCH + col] = tanhf(acc[j] + offB[col]) * RADIUS_F;
            }
        } else {
#pragma unroll
            for (int j = 0; j < 4; j++) {
                int c2 = cl + 32 * j;
                wl[(long)n * 128 + c2] = acc[j] + wB[c2];
            }
        }
    }
}

// Per-(cam,query) sampling. One wave per task; XCD-pinned task ranges.
// (256,4): VGPR cap 128 — holds w_[16] + in-flight loads without spilling
// (the (256,8)/VGPR=32 variant spilled ~270 MB to scratch — round 16).
__global__ void __launch_bounds__(256, 4) sample_cam_k(
        const unsigned short* __restrict__ feat_t,  // [CAMS][NPIX][CCH] bf16
        const float* __restrict__ refp,             // [CAMS][N][PIP][2]
        const int* __restrict__ bev,                // [CAMS][N][PIP]
        const float* __restrict__ offsets,          // [N][256]
        const float* __restrict__ wl,               // [N][128]
        float* __restrict__ cam_out,                // [CAMS][N][256]
        int N, int per_xcd) {
    int xcd = blockIdx.x & 7;
    int local = (blockIdx.x >> 3) * 4 + (threadIdx.x >> 6);
    if (local >= per_xcd) return;
    long task = (long)xcd * per_xcd + local;
    if (task >= (long)CAMS * N) return;
    int cam = (int)(task / N);
    int n = (int)(task - (long)cam * N);

    int l = threadIdx.x & 63;
    int h = l >> 3;

    const int* bv = bev + ((long)cam * N + n) * 4;
    int m0 = bv[0], m1 = bv[1], m2 = bv[2], m3 = bv[3];
    float* outp = cam_out + ((long)cam * N + n) * CCH + (l << 2);
    if (!(m0 | m1 | m2 | m3)) {
        *(float4*)outp = make_float4(0.f, 0.f, 0.f, 0.f);
        return;
    }

    const float* rp = refp + ((long)cam * N + n) * 8;
    const float4* offn = (const float4*)(offsets + (long)n * CCH + (h << 5));
    const float4* wln = (const float4*)(wl + (long)n * 128 + (h << 4));

    float4 wl0, wl1, wl2, wl3;
    float mmax = -1e30f;
    if (m0) { wl0 = wln[0]; mmax = fmaxf(mmax, fmaxf(fmaxf(wl0.x, wl0.y), fmaxf(wl0.z, wl0.w))); }
    if (m1) { wl1 = wln[1]; mmax = fmaxf(mmax, fmaxf(fmaxf(wl1.x, wl1.y), fmaxf(wl1.z, wl1.w))); }
    if (m2) { wl2 = wln[2]; mmax = fmaxf(mmax, fmaxf(fmaxf(wl2.x, wl2.y), fmaxf(wl2.z, wl2.w))); }
    if (m3) { wl3 = wln[3]; mmax = fmaxf(mmax, fmaxf(fmaxf(wl3.x, wl3.y), fmaxf(wl3.z, wl3.w))); }

    float w_[KK];
#pragma unroll
    for (int k = 0; k < KK; k++) w_[k] = 0.f;
    float ssum = 0.f;
    if (m0) {
        w_[0] = __expf(wl0.x - mmax); w_[1] = __expf(wl0.y - mmax);
        w_[2] = __expf(wl0.z - mmax); w_[3] = __expf(wl0.w - mmax);
        ssum += w_[0] + w_[1] + w_[2] + w_[3];
    }
    if (m1) {
        w_[4] = __expf(wl1.x - mmax); w_[5] = __expf(wl1.y - mmax);
        w_[6] = __expf(wl1.z - mmax); w_[7] = __expf(wl1.w - mmax);
        ssum += w_[4] + w_[5] + w_[6] + w_[7];
    }
    if (m2) {
        w_[8] = __expf(wl2.x - mmax); w_[9] = __expf(wl2.y - mmax);
        w_[10] = __expf(wl2.z - mmax); w_[11] = __expf(wl2.w - mmax);
        ssum += w_[8] + w_[9] + w_[10] + w_[11];
    }
    if (m3) {
        w_[12] = __expf(wl3.x - mmax); w_[13] = __expf(wl3.y - mmax);
        w_[14] = __expf(wl3.z - mmax); w_[15] = __expf(wl3.w - mmax);
        ssum += w_[12] + w_[13] + w_[14] + w_[15];
    }
    float inv = 1.f / ssum;

    const ushort4* fcam = (const ushort4*)(feat_t + (long)cam * NPIX * CCH) + l;
    float ax = 0.f, ay = 0.f, az = 0.f, aw = 0.f;

#pragma unroll
    for (int pip = 0; pip < PIP; pip++) {
        int vis = (pip == 0) ? m0 : (pip == 1) ? m1 : (pip == 2) ? m2 : m3;
        if (!vis) continue;
        float rx = rp[pip * 2 + 0];
        float ry = rp[pip * 2 + 1];
        float4 oa = offn[pip * 2];
        float4 ob = offn[pip * 2 + 1];
        float px[PP] = {oa.x, oa.z, ob.x, ob.z};
        float py[PP] = {oa.y, oa.w, ob.y, ob.w};
#pragma unroll
        for (int p = 0; p < PP; p++) {
            float wgt = w_[pip * PP + p];
            float x = fmaf(rx + px[p], (float)WW, -0.5f);
            float y = fmaf(ry + py[p], (float)HH, -0.5f);
            float x0f = floorf(x), y0f = floorf(y);
            float fx = x - x0f, fy = y - y0f;
            int ix = (int)x0f, iy = (int)y0f;
            int ix0 = min(max(ix, 0), WW - 1);
            int ix1 = min(max(ix + 1, 0), WW - 1);
            int iy0 = min(max(iy, 0), HH - 1);
            int iy1 = min(max(iy + 1, 0), HH - 1);
            float wx0 = (1.f - fx) * (((ix >= 0) & (ix < WW)) ? 1.f : 0.f);
            float wx1 = fx * (((ix + 1 >= 0) & (ix + 1 < WW)) ? 1.f : 0.f);
            float wy0 = (1.f - fy) * (((iy >= 0) & (iy < HH)) ? 1.f : 0.f);
            float wy1 = fy * (((iy + 1 >= 0) & (iy + 1 < HH)) ? 1.f : 0.f);
            const ushort4 u00 = fcam[(iy0 * WW + ix0) * (CCH / 4)];
            const ushort4 u01 = fcam[(iy0 * WW + ix1) * (CCH / 4)];
            const ushort4 u10 = fcam[(iy1 * WW + ix0) * (CCH / 4)];
            const ushort4 u11 = fcam[(iy1 * WW + ix1) * (CCH / 4)];
            float a00 = wgt * wy0 * wx0;
            float a01 = wgt * wy0 * wx1;
            float a10 = wgt * wy1 * wx0;
            float a11 = wgt * wy1 * wx1;
            ax = fmaf(a00, bf2f(u00.x), ax); ay = fmaf(a00, bf2f(u00.y), ay);
            az = fmaf(a00, bf2f(u00.z), az); aw = fmaf(a00, bf2f(u00.w), aw);
            ax = fmaf(a01, bf2f(u01.x), ax); ay = fmaf(a01, bf2f(u01.y), ay);
            az = fmaf(a01, bf2f(u01.z), az); aw = fmaf(a01, bf2f(u01.w), aw);
            ax = fmaf(a10, bf2f(u10.x), ax); ay = fmaf(a10, bf2f(u10.y), ay);
            az = fmaf(a10, bf2f(u10.z), az); aw = fmaf(a10, bf2f(u10.w), aw);
            ax = fmaf(a11, bf2f(u11.x), ax); ay = fmaf(a11, bf2f(u11.y), ay);
            az = fmaf(a11, bf2f(u11.z), az); aw = fmaf(a11, bf2f(u11.w), aw);
        }
    }
    *(float4*)outp = make_float4(ax * inv, ay * inv, az * inv, aw * inv);
}

// Dense layer 2 with fused 6-camera sum + count: grid (313, 2);
// block = 8n x 128c; thread = 1n x 4c. No min-wave hint.
__global__ void __launch_bounds__(256) outfuse14_k(const float* __restrict__ camob,
                                                   const int* __restrict__ bev,
                                                   const float* __restrict__ outTi, // f4[64][256]
                                                   const float* __restrict__ outB,
                                                   float* __restrict__ out, int N) {
    __shared__ float4 a_lds[64][9];
    __shared__ float inv_s[8];
    int t = threadIdx.x;
    int n0 = blockIdx.x * 8;
    int colg = blockIdx.y;            // 0..1
    int nn = t >> 5;
    int k4 = t & 31;
    int n = n0 + nn;
    int ncl = min(n, N - 1);
    {
        float4 s0 = make_float4(0.f, 0.f, 0.f, 0.f);
        float4 s1 = make_float4(0.f, 0.f, 0.f, 0.f);
#pragma unroll
        for (int cam = 0; cam < CAMS; cam++) {
            const float4* cr = (const float4*)(camob + ((long)cam * N + ncl) * CCH);
            float4 v0 = cr[k4];
            float4 v1 = cr[k4 + 32];
            s0.x += v0.x; s0.y += v0.y; s0.z += v0.z; s0.w += v0.w;
            s1.x += v1.x; s1.y += v1.y; s1.z += v1.z; s1.w += v1.w;
        }
        bool ok = n < N;
        a_lds[k4][nn] = ok ? s0 : make_float4(0.f, 0.f, 0.f, 0.f);
        a_lds[k4 + 32][nn] = ok ? s1 : make_float4(0.f, 0.f, 0.f, 0.f);
    }
    if (k4 == 0) {
        int cnt = 0;
        const int4* bv4 = (const int4*)bev;
#pragma unroll
        for (int cam = 0; cam < CAMS; cam++) {
            int4 bv = bv4[(long)cam * N + ncl];
            cnt += (bv.x | bv.y | bv.z | bv.w) ? 1 : 0;
        }
        inv_s[nn] = 1.f / (float)max(cnt, 1);
    }
    __syncthreads();

    int cl = k4;
    const float4* wp = (const float4*)outTi + colg * 128 + cl;
    float acc[4] = {0.f, 0.f, 0.f, 0.f};

#pragma unroll 2
    for (int kg = 0; kg < 64; kg++) {
        float4 a = a_lds[kg][nn];
        const float4* wk = wp + (long)kg * 256;
#pragma unroll
        for (int j = 0; j < 4; j++) {
            float4 wv = wk[32 * j];
            acc[j] = fmaf(a.w, wv.w, fmaf(a.z, wv.z, fmaf(a.y, wv.y, fmaf(a.x, wv.x, acc[j]))));
        }
    }

    if (n < N) {
        float inv = inv_s[nn];
#pragma unroll
        for (int j = 0; j < 4; j++) {
            int col = colg * 128 + cl + 32 * j;
            out[(long)n * CCH + col] = fmaf(acc[j], inv, outB[col]);
        }
    }
}

extern "C" void kernel_launch(void* const* d_in, const int* in_sizes, int n_in,
                              void* d_out, int out_size, void* d_ws, size_t ws_size,
                              hipStream_t stream) {
    const float* query    = (const float*)d_in[0];
    const float* imfeat   = (const float*)d_in[1];
    const float* refp     = (const float*)d_in[2];
    const int*   bev      = (const int*)d_in[3];
    const float* offset_w = (const float*)d_in[4];
    const float* offset_b = (const float*)d_in[5];
    const float* weight_w = (const float*)d_in[6];
    const float* weight_b = (const float*)d_in[7];
    const float* out_w    = (const float*)d_in[8];
    const float* out_b    = (const float*)d_in[9];
    float* out = (float*)d_out;

    int N = in_sizes[0] / CCH;  // 2500

    float* ws = (float*)d_ws;
    unsigned short* feat_t = (unsigned short*)ws;              // 6*3680*256 bf16
    float* WCi    = ws + (size_t)CAMS * NPIX * CCH / 2;        // f4[64][384]
    float* outTi  = WCi + (size_t)CCH * NC;                    // f4[64][256]
    float* offs   = outTi + (size_t)CCH * CCH;                 // N*256
    float* wl     = offs + (size_t)N * CCH;                    // N*128
    float* camob  = wl + (size_t)N * 128;                      // CAMS*N*256

    prep4_k<<<FEATB + 40, 256, 0, stream>>>(imfeat, feat_t, offset_w, weight_w,
                                            out_w, WCi, outTi);

    int nb8 = (N + 7) / 8;   // 313
    qgemm14_k<<<dim3(nb8, 3), 256, 0, stream>>>(query, WCi, offset_b, weight_b,
                                                offs, wl, N);

    int T = CAMS * N;
    int per_xcd = (T + 7) / 8;
    int blocks = 8 * ((per_xcd + 3) / 4);
    sample_cam_k<<<blocks, 256, 0, stream>>>(feat_t, refp, bev, offs, wl, camob,
                                             N, per_xcd);

    outfuse14_k<<<dim3(nb8, 2), 256, 0, stream>>>(camob, bev, outTi, out_b, out, N);
}

// Round 19
// 98.904 us; speedup vs baseline: 1.7802x; 1.0664x over previous
//
#include <hip/hip_runtime.h>
#include <math.h>

#define CAMS 6
#define CCH 256
#define HH 46
#define WW 80
#define NPIX (HH * WW)
#define HEADS 8
#define PIP 4
#define PP 4
#define KK 16
#define RADIUS_F 0.12f
#define NC 384        // combined qgemm output width: 256 offsets + 128 logits
#define FEATB (58 * 4 * CAMS)   // feat-transpose blocks in prep
#define QTB (40 * 4)            // query-transpose blocks in prep

typedef float vf4 __attribute__((ext_vector_type(4)));   // native vec for nontemporal builtins

__device__ __forceinline__ unsigned short f2bf(float f) {
    unsigned int x = __float_as_uint(f);
    unsigned int r = (x + 0x7FFFu + ((x >> 16) & 1u)) >> 16;  // RNE
    return (unsigned short)r;
}
__device__ __forceinline__ float bf2f(unsigned short u) {
    return __uint_as_float(((unsigned int)u) << 16);
}
__device__ __forceinline__ void nt_store4(float* p, float a, float b, float c, float d) {
    vf4 v = {a, b, c, d};
    __builtin_nontemporal_store(v, (vf4*)p);
}

// prep2_k (round-11 version, best measured):
//  [0, FEATB)            : LDS-tiled feat transpose + bf16 convert
//  [FEATB, FEATB+40)     : weight transposes -> f4[kg][col] = W[col][4kg..4kg+3]
//  [FEATB+40, +40+QTB)   : query transpose -> qTi f4[kg][n]
__global__ void __launch_bounds__(256) prep2_k(const float* __restrict__ imfeat,
                                               unsigned short* __restrict__ feat_t,
                                               const float* __restrict__ offw,
                                               const float* __restrict__ ww,
                                               const float* __restrict__ outw,
                                               const float* __restrict__ query,
                                               float* __restrict__ WCi,
                                               float* __restrict__ outTi,
                                               float* __restrict__ qTi,
                                               int N) {
    __shared__ float tile[64][65];
    int b = blockIdx.x;
    int tj = threadIdx.x & 63;
    int ti = threadIdx.x >> 6;
    if (b < FEATB) {
        int px = b % 58, rest = b / 58;
        int r0 = (rest % 4) * 64;
        int cam = rest / 4;
        int p0 = px * 64;
        const float* src = imfeat + ((long)cam * CCH + r0) * NPIX + p0;
#pragma unroll
        for (int k = 0; k < 64; k += 4) {
            if (p0 + tj < NPIX) tile[ti + k][tj] = src[(long)(ti + k) * NPIX + tj];
        }
        __syncthreads();
        unsigned short* dst = feat_t + ((long)cam * NPIX + p0) * CCH + r0;
#pragma unroll
        for (int k = 0; k < 64; k += 4) {
            if (p0 + ti + k < NPIX) dst[(long)(ti + k) * CCH + tj] = f2bf(tile[tj][ti + k]);
        }
    } else if (b < FEATB + 40) {
        int c = b - FEATB;
        const float* src;
        float* dst;
        int tr, tc, dcols, dcol0;
        if (c < 16)      { src = offw; dst = WCi;   tr = c >> 2;        tc = c & 3;         dcols = NC;  dcol0 = 0; }
        else if (c < 24) { src = ww;   dst = WCi;   tr = (c - 16) & 1;  tc = (c - 16) >> 1; dcols = NC;  dcol0 = 256; }
        else             { src = outw; dst = outTi; tr = (c - 24) >> 2; tc = (c - 24) & 3;  dcols = 256; dcol0 = 0; }
#pragma unroll
        for (int k = 0; k < 64; k += 4)
            tile[ti + k][tj] = src[(long)(tr * 64 + ti + k) * CCH + tc * 64 + tj];
        __syncthreads();
        int col = dcol0 + tr * 64 + tj;
#pragma unroll
        for (int q = ti; q < 16; q += 4) {
            float4 v = make_float4(tile[tj][4 * q + 0], tile[tj][4 * q + 1],
                                   tile[tj][4 * q + 2], tile[tj][4 * q + 3]);
            ((float4*)dst)[(long)(tc * 16 + q) * dcols + col] = v;
        }
    } else {
        int c = b - FEATB - 40;        // 0..159
        int nt = c % 40, ct = c / 40;  // n-tile, c-tile
        int n0 = nt * 64, c0 = ct * 64;
#pragma unroll
        for (int k = 0; k < 64; k += 4) {
            int row = ti + k;
            tile[row][tj] = (n0 + row < N) ? query[(long)(n0 + row) * CCH + c0 + tj] : 0.f;
        }
        __syncthreads();
        int n = n0 + tj;
        if (n < N) {
#pragma unroll
            for (int q = ti; q < 16; q += 4) {
                float4 v = make_float4(tile[tj][4 * q + 0], tile[tj][4 * q + 1],
                                       tile[tj][4 * q + 2], tile[tj][4 * q + 3]);
                ((float4*)qTi)[(long)((c0 >> 2) + q) * N + n] = v;
            }
        }
    }
}

// Dense layer 1 (round-11 version): lane = query row. Activations: private
// coalesced float4 from qTi (VMEM pipe). Weights: wave-uniform -> scalar
// loads on the SMEM pipe (one per wave, scalar-cache resident).
__global__ void __launch_bounds__(256) qgemm7_k(const float* __restrict__ qTi,
                                                const float* __restrict__ WCi,  // f4[64][NC]
                                                const float* __restrict__ offB,
                                                const float* __restrict__ wB,
                                                float* __restrict__ offsets,    // [N][256]
                                                float* __restrict__ wl,         // [N][128]
                                                int N) {
    int n = blockIdx.x * 256 + threadIdx.x;
    int col0 = blockIdx.y * 8;
    int nc = min(n, N - 1);
    const float4* ap = (const float4*)qTi + nc;
    const float4* wp = (const float4*)WCi + col0;
    float acc[8] = {0.f, 0.f, 0.f, 0.f, 0.f, 0.f, 0.f, 0.f};
#pragma unroll 4
    for (int kg = 0; kg < 64; kg++) {
        float4 a = ap[(long)kg * N];
#pragma unroll
        for (int j = 0; j < 8; j++) {
            float4 wv = wp[(long)kg * NC + j];
            acc[j] = fmaf(a.w, wv.w, fmaf(a.z, wv.z, fmaf(a.y, wv.y, fmaf(a.x, wv.x, acc[j]))));
        }
    }
    if (n < N) {
        if (col0 < 256) {
#pragma unroll
            for (int j = 0; j < 8; j++)
                offsets[(long)n * CCH + col0 + j] = tanhf(acc[j] + offB[col0 + j]) * RADIUS_F;
        } else {
#pragma unroll
            for (int j = 0; j < 8; j++)
                wl[(long)n * 128 + (col0 - 256) + j] = acc[j] + wB[(col0 - 256) + j];
        }
    }
}

// Per-(cam,query) sampling with SINGLE-CAM XCD schedule:
//   XCD 0-3 -> cams 0-3 (N tasks each); cam 4 -> XCDs {4,6}; cam 5 -> {5,7}
//   (N/2 tasks each). Every XCD's feat footprint = one cam = 1.88 MB bf16
//   (half its 4 MB L2). cam_out stores are non-temporal so the 15 MB write
//   stream doesn't evict feat lines (round-16 FETCH=163MB ~ 0% L2 hit).
__global__ void __launch_bounds__(256, 4) sample_cam2_k(
        const unsigned short* __restrict__ feat_t,  // [CAMS][NPIX][CCH] bf16
        const float* __restrict__ refp,             // [CAMS][N][PIP][2]
        const int* __restrict__ bev,                // [CAMS][N][PIP]
        const float* __restrict__ offsets,          // [N][256]
        const float* __restrict__ wl,               // [N][128]
        float* __restrict__ cam_out,                // [CAMS][N][256]
        int N) {
    int xcd = blockIdx.x & 7;
    int idx = (blockIdx.x >> 3) * 4 + (threadIdx.x >> 6);
    int half = N >> 1;
    int cnt = (xcd < 4) ? N : half;
    if (idx >= cnt) return;                        // wave-uniform
    int cam = (xcd < 6) ? xcd : (xcd - 2);
    int n = ((xcd >= 6) ? half : 0) + idx;

    int l = threadIdx.x & 63;
    int h = l >> 3;

    const int* bv = bev + ((long)cam * N + n) * 4;
    int m0 = bv[0], m1 = bv[1], m2 = bv[2], m3 = bv[3];
    float* outp = cam_out + ((long)cam * N + n) * CCH + (l << 2);
    if (!(m0 | m1 | m2 | m3)) {
        nt_store4(outp, 0.f, 0.f, 0.f, 0.f);
        return;
    }

    const float* rp = refp + ((long)cam * N + n) * 8;
    const float4* offn = (const float4*)(offsets + (long)n * CCH + (h << 5));
    const float4* wln = (const float4*)(wl + (long)n * 128 + (h << 4));

    float4 wl0, wl1, wl2, wl3;
    float mmax = -1e30f;
    if (m0) { wl0 = wln[0]; mmax = fmaxf(mmax, fmaxf(fmaxf(wl0.x, wl0.y), fmaxf(wl0.z, wl0.w))); }
    if (m1) { wl1 = wln[1]; mmax = fmaxf(mmax, fmaxf(fmaxf(wl1.x, wl1.y), fmaxf(wl1.z, wl1.w))); }
    if (m2) { wl2 = wln[2]; mmax = fmaxf(mmax, fmaxf(fmaxf(wl2.x, wl2.y), fmaxf(wl2.z, wl2.w))); }
    if (m3) { wl3 = wln[3]; mmax = fmaxf(mmax, fmaxf(fmaxf(wl3.x, wl3.y), fmaxf(wl3.z, wl3.w))); }

    float w_[KK];
#pragma unroll
    for (int k = 0; k < KK; k++) w_[k] = 0.f;
    float ssum = 0.f;
    if (m0) {
        w_[0] = __expf(wl0.x - mmax); w_[1] = __expf(wl0.y - mmax);
        w_[2] = __expf(wl0.z - mmax); w_[3] = __expf(wl0.w - mmax);
        ssum += w_[0] + w_[1] + w_[2] + w_[3];
    }
    if (m1) {
        w_[4] = __expf(wl1.x - mmax); w_[5] = __expf(wl1.y - mmax);
        w_[6] = __expf(wl1.z - mmax); w_[7] = __expf(wl1.w - mmax);
        ssum += w_[4] + w_[5] + w_[6] + w_[7];
    }
    if (m2) {
        w_[8] = __expf(wl2.x - mmax); w_[9] = __expf(wl2.y - mmax);
        w_[10] = __expf(wl2.z - mmax); w_[11] = __expf(wl2.w - mmax);
        ssum += w_[8] + w_[9] + w_[10] + w_[11];
    }
    if (m3) {
        w_[12] = __expf(wl3.x - mmax); w_[13] = __expf(wl3.y - mmax);
        w_[14] = __expf(wl3.z - mmax); w_[15] = __expf(wl3.w - mmax);
        ssum += w_[12] + w_[13] + w_[14] + w_[15];
    }
    float inv = 1.f / ssum;

    const ushort4* fcam = (const ushort4*)(feat_t + (long)cam * NPIX * CCH) + l;
    float ax = 0.f, ay = 0.f, az = 0.f, aw = 0.f;

#pragma unroll
    for (int pip = 0; pip < PIP; pip++) {
        int vis = (pip == 0) ? m0 : (pip == 1) ? m1 : (pip == 2) ? m2 : m3;
        if (!vis) continue;
        float rx = rp[pip * 2 + 0];
        float ry = rp[pip * 2 + 1];
        float4 oa = offn[pip * 2];
        float4 ob = offn[pip * 2 + 1];
        float px[PP] = {oa.x, oa.z, ob.x, ob.z};
        float py[PP] = {oa.y, oa.w, ob.y, ob.w};
#pragma unroll
        for (int p = 0; p < PP; p++) {
            float wgt = w_[pip * PP + p];
            float x = fmaf(rx + px[p], (float)WW, -0.5f);
            float y = fmaf(ry + py[p], (float)HH, -0.5f);
            float x0f = floorf(x), y0f = floorf(y);
            float fx = x - x0f, fy = y - y0f;
            int ix = (int)x0f, iy = (int)y0f;
            int ix0 = min(max(ix, 0), WW - 1);
            int ix1 = min(max(ix + 1, 0), WW - 1);
            int iy0 = min(max(iy, 0), HH - 1);
            int iy1 = min(max(iy + 1, 0), HH - 1);
            float wx0 = (1.f - fx) * (((ix >= 0) & (ix < WW)) ? 1.f : 0.f);
            float wx1 = fx * (((ix + 1 >= 0) & (ix + 1 < WW)) ? 1.f : 0.f);
            float wy0 = (1.f - fy) * (((iy >= 0) & (iy < HH)) ? 1.f : 0.f);
            float wy1 = fy * (((iy + 1 >= 0) & (iy + 1 < HH)) ? 1.f : 0.f);
            const ushort4 u00 = fcam[(iy0 * WW + ix0) * (CCH / 4)];
            const ushort4 u01 = fcam[(iy0 * WW + ix1) * (CCH / 4)];
            const ushort4 u10 = fcam[(iy1 * WW + ix0) * (CCH / 4)];
            const ushort4 u11 = fcam[(iy1 * WW + ix1) * (CCH / 4)];
            float a00 = wgt * wy0 * wx0;
            float a01 = wgt * wy0 * wx1;
            float a10 = wgt * wy1 * wx0;
            float a11 = wgt * wy1 * wx1;
            ax = fmaf(a00, bf2f(u00.x), ax); ay = fmaf(a00, bf2f(u00.y), ay);
            az = fmaf(a00, bf2f(u00.z), az); aw = fmaf(a00, bf2f(u00.w), aw);
            ax = fmaf(a01, bf2f(u01.x), ax); ay = fmaf(a01, bf2f(u01.y), ay);
            az = fmaf(a01, bf2f(u01.z), az); aw = fmaf(a01, bf2f(u01.w), aw);
            ax = fmaf(a10, bf2f(u10.x), ax); ay = fmaf(a10, bf2f(u10.y), ay);
            az = fmaf(a10, bf2f(u10.z), az); aw = fmaf(a10, bf2f(u10.w), aw);
            ax = fmaf(a11, bf2f(u11.x), ax); ay = fmaf(a11, bf2f(u11.y), ay);
            az = fmaf(a11, bf2f(u11.z), az); aw = fmaf(a11, bf2f(u11.w), aw);
        }
    }
    nt_store4(outp, ax * inv, ay * inv, az * inv, aw * inv);
}

// camsum + transpose: fsumTi f4[kg][n] = sum_cam cam_out[cam][n][4kg..4kg+3]
__global__ void __launch_bounds__(256) camsum_t_k(const float* __restrict__ cam_out,
                                                  float* __restrict__ fsumTi, int N) {
    __shared__ float4 lds[16][33];
    int t = threadIdx.x;
    int n0 = blockIdx.x * 32;
    int kg0 = blockIdx.y * 16;
    const float4* src = (const float4*)cam_out;
#pragma unroll
    for (int pass = 0; pass < 2; pass++) {
        int item = t + pass * 256;
        int row = item >> 4;      // 0..31
        int c = item & 15;        // 0..15
        int n = n0 + row;
        float4 s = make_float4(0.f, 0.f, 0.f, 0.f);
        if (n < N) {
#pragma unroll
            for (int cam = 0; cam < CAMS; cam++) {
                float4 v = src[((long)cam * N + n) * 64 + kg0 + c];
                s.x += v.x; s.y += v.y; s.z += v.z; s.w += v.w;
            }
        }
        lds[c][row] = s;
    }
    __syncthreads();
    float4* dst = (float4*)fsumTi;
#pragma unroll
    for (int pass = 0; pass < 2; pass++) {
        int item = t + pass * 256;
        int k = item >> 5;        // 0..15
        int row = item & 31;
        int n = n0 + row;
        if (n < N) dst[(long)(kg0 + k) * N + n] = lds[k][row];
    }
}

// Dense layer 2 (round-11 version): no-LDS, scalar weights, coalesced acts.
__global__ void __launch_bounds__(256) outproj7_k(const float* __restrict__ fsumTi,
                                                  const int* __restrict__ bev,
                                                  const float* __restrict__ outTi, // f4[64][256]
                                                  const float* __restrict__ outB,
                                                  float* __restrict__ out, int N) {
    int n = blockIdx.x * 256 + threadIdx.x;
    int col0 = blockIdx.y * 8;
    int nc = min(n, N - 1);
    const float4* ap = (const float4*)fsumTi + nc;
    const float4* wp = (const float4*)outTi + col0;
    const int4* bv4 = (const int4*)bev;
    int cnt = 0;
#pragma unroll
    for (int cam = 0; cam < CAMS; cam++) {
        int4 bv = bv4[(long)cam * N + nc];
        cnt += (bv.x | bv.y | bv.z | bv.w) ? 1 : 0;
    }
    float inv = 1.f / (float)max(cnt, 1);
    float acc[8] = {0.f, 0.f, 0.f, 0.f, 0.f, 0.f, 0.f, 0.f};
#pragma unroll 4
    for (int kg = 0; kg < 64; kg++) {
        float4 a = ap[(long)kg * N];
#pragma unroll
        for (int j = 0; j < 8; j++) {
            float4 wv = wp[(long)kg * CCH + j];
            acc[j] = fmaf(a.w, wv.w, fmaf(a.z, wv.z, fmaf(a.y, wv.y, fmaf(a.x, wv.x, acc[j]))));
        }
    }
    if (n < N) {
#pragma unroll
        for (int j = 0; j < 8; j++)
            out[(long)n * CCH + col0 + j] = fmaf(acc[j], inv, outB[col0 + j]);
    }
}

extern "C" void kernel_launch(void* const* d_in, const int* in_sizes, int n_in,
                              void* d_out, int out_size, void* d_ws, size_t ws_size,
                              hipStream_t stream) {
    const float* query    = (const float*)d_in[0];
    const float* imfeat   = (const float*)d_in[1];
    const float* refp     = (const float*)d_in[2];
    const int*   bev      = (const int*)d_in[3];
    const float* offset_w = (const float*)d_in[4];
    const float* offset_b = (const float*)d_in[5];
    const float* weight_w = (const float*)d_in[6];
    const float* weight_b = (const float*)d_in[7];
    const float* out_w    = (const float*)d_in[8];
    const float* out_b    = (const float*)d_in[9];
    float* out = (float*)d_out;

    int N = in_sizes[0] / CCH;  // 2500

    float* ws = (float*)d_ws;
    unsigned short* feat_t = (unsigned short*)ws;              // 6*3680*256 bf16
    float* WCi    = ws + (size_t)CAMS * NPIX * CCH / 2;        // f4[64][384]
    float* outTi  = WCi + (size_t)CCH * NC;                    // f4[64][256]
    float* offs   = outTi + (size_t)CCH * CCH;                 // N*256
    float* wl     = offs + (size_t)N * CCH;                    // N*128
    float* camob  = wl + (size_t)N * 128;                      // CAMS*N*256
    float* qTi    = camob + (size_t)CAMS * N * CCH;            // 64*N*4
    float* fsumTi = qTi + (size_t)64 * N * 4;                  // 64*N*4

    prep2_k<<<FEATB + 40 + QTB, 256, 0, stream>>>(imfeat, feat_t, offset_w, weight_w,
                                                  out_w, query, WCi, outTi, qTi, N);

    int nblk = (N + 255) / 256;   // 10
    qgemm7_k<<<dim3(nblk, 48), 256, 0, stream>>>(qTi, WCi, offset_b, weight_b,
                                                 offs, wl, N);

    // single-cam XCD schedule: max N tasks per XCD, 4 tasks (waves) per block
    int blocks = 8 * ((N + 3) / 4);   // 5000
    sample_cam2_k<<<blocks, 256, 0, stream>>>(feat_t, refp, bev, offs, wl, camob, N);

    camsum_t_k<<<dim3((N + 31) / 32, 4), 256, 0, stream>>>(camob, fsumTi, N);

    outproj7_k<<<dim3(nblk, 32), 256, 0, stream>>>(fsumTi, bev, outTi, out_b, out, N);
}